// Round 1
// baseline (753.658 us; speedup 1.0000x reference)
//
#include <hip/hip_runtime.h>
#include <hip/hip_bf16.h>

#define LSEQ 2048
#define DMODEL 1024
#define OUTD 512
#define DSTATE 16
#define DINNER 2048
#define DTRANK 64

typedef __attribute__((ext_vector_type(8))) short bf16x8;
typedef __attribute__((ext_vector_type(4))) float f32x4;

__device__ __forceinline__ ushort f2b(float f) {
  __hip_bfloat16 h = __float2bfloat16(f);
  return *reinterpret_cast<ushort*>(&h);
}
__device__ __forceinline__ float b2f(ushort u) {
  __hip_bfloat16 h = *reinterpret_cast<__hip_bfloat16*>(&u);
  return __bfloat162float(h);
}

// ---------------- prep kernels ----------------
__global__ __launch_bounds__(256) void convert_k(const float* __restrict__ in,
                                                 ushort* __restrict__ out, int n) {
  int i = blockIdx.x * 256 + threadIdx.x;
  if (i < n) out[i] = f2b(in[i]);
}

__global__ __launch_bounds__(256) void tokens_k(const float* __restrict__ img,
                                                const float* __restrict__ txt,
                                                ushort* __restrict__ out) {
  int i = blockIdx.x * 256 + threadIdx.x;  // L*DMODEL
  int r = i >> 10, c = i & 1023;
  float v = (c < 512) ? img[r * 512 + c] : txt[r * 512 + c - 512];
  out[i] = f2b(v);
}

__global__ __launch_bounds__(256) void xproj_pad_k(const float* __restrict__ w,
                                                   ushort* __restrict__ out) {
  int i = blockIdx.x * 256 + threadIdx.x;  // 128*2048
  int r = i >> 11, c = i & 2047;
  out[i] = (r < 96) ? f2b(w[r * 2048 + c]) : (ushort)0;
}

// A' = [hi(img) | lo(img) | hi(img)], B' = [hi(txt) | hi(txt) | lo(txt)]
__global__ __launch_bounds__(256) void attn_ext_k(const float* __restrict__ img,
                                                  const float* __restrict__ txt,
                                                  ushort* __restrict__ Ae,
                                                  ushort* __restrict__ Be) {
  int i = blockIdx.x * 256 + threadIdx.x;  // L*512
  int r = i >> 9, c = i & 511;
  float a = img[i], b = txt[i];
  ushort ah = f2b(a); ushort al = f2b(a - b2f(ah));
  ushort bh = f2b(b); ushort bl = f2b(b - b2f(bh));
  size_t base = (size_t)r * 1536;
  Ae[base + c] = ah; Ae[base + 512 + c] = al; Ae[base + 1024 + c] = ah;
  Be[base + c] = bh; Be[base + 512 + c] = bh; Be[base + 1024 + c] = bl;
}

__global__ __launch_bounds__(256) void textT_k(const float* __restrict__ txt,
                                               ushort* __restrict__ out) {
  __shared__ float tile[32][33];
  int bx = blockIdx.x, by = blockIdx.y;          // bx over 512/32, by over 2048/32
  int tx = threadIdx.x & 31, ty = threadIdx.x >> 5;  // 32 x 8
  for (int j = 0; j < 32; j += 8)
    tile[ty + j][tx] = txt[(size_t)(by * 32 + ty + j) * 512 + bx * 32 + tx];
  __syncthreads();
  for (int j = 0; j < 32; j += 8)
    out[(size_t)(bx * 32 + ty + j) * 2048 + by * 32 + tx] = f2b(tile[tx][ty + j]);
}

__global__ __launch_bounds__(256) void dtr_k(const float* __restrict__ xdbl,
                                             ushort* __restrict__ out) {
  int i = blockIdx.x * 256 + threadIdx.x;  // L*64
  int r = i >> 6, c = i & 63;
  out[i] = f2b(xdbl[r * 128 + c]);
}

// ---------------- GEMM (bf16 MFMA, 128x128 tile, BK=32) ----------------
// C[m,n] = sum_k A[m,k]*B[n,k]  (both row-major, K contiguous; "NT")
// EPI: 0 = store fp32, 1 = softplus(C + bias[n]), 2 = atomicAdd (split-K)
template <int EPI>
__global__ __launch_bounds__(256) void gemm_bf16_k(
    const ushort* __restrict__ A, const ushort* __restrict__ B,
    float* __restrict__ C, const float* __restrict__ bias,
    int M, int N, int K, int lda, int ldb, int ldc, int kPerSplit) {
  __shared__ ushort As[128 * 32];
  __shared__ ushort Bs[128 * 32];
  const int bm = blockIdx.y * 128, bn = blockIdx.x * 128;
  const int tid = threadIdx.x;
  const int w = tid >> 6, lane = tid & 63;
  const int wr = (w >> 1) * 64, wc = (w & 1) * 64;
  const int lr = lane & 15, lk = lane >> 4;
  const int srow = tid >> 2, scol = (tid & 3) * 8;
  const int k0 = blockIdx.z * kPerSplit;
  const int k1 = k0 + kPerSplit;
  f32x4 acc[4][4] = {};
  for (int kt = k0; kt < k1; kt += 32) {
    *(int4*)&As[srow * 32 + scol] =
        *(const int4*)&A[(size_t)(bm + srow) * lda + kt + scol];
    *(int4*)&As[(srow + 64) * 32 + scol] =
        *(const int4*)&A[(size_t)(bm + srow + 64) * lda + kt + scol];
    *(int4*)&Bs[srow * 32 + scol] =
        *(const int4*)&B[(size_t)(bn + srow) * ldb + kt + scol];
    *(int4*)&Bs[(srow + 64) * 32 + scol] =
        *(const int4*)&B[(size_t)(bn + srow + 64) * ldb + kt + scol];
    __syncthreads();
    bf16x8 af[4], bfr[4];
#pragma unroll
    for (int i = 0; i < 4; i++) af[i] = *(bf16x8*)&As[(wr + i * 16 + lr) * 32 + lk * 8];
#pragma unroll
    for (int i = 0; i < 4; i++) bfr[i] = *(bf16x8*)&Bs[(wc + i * 16 + lr) * 32 + lk * 8];
#pragma unroll
    for (int mi = 0; mi < 4; mi++)
#pragma unroll
      for (int ni = 0; ni < 4; ni++)
        acc[mi][ni] = __builtin_amdgcn_mfma_f32_16x16x32_bf16(af[mi], bfr[ni],
                                                              acc[mi][ni], 0, 0, 0);
    __syncthreads();
  }
#pragma unroll
  for (int mi = 0; mi < 4; mi++) {
#pragma unroll
    for (int ni = 0; ni < 4; ni++) {
      int row = bm + wr + mi * 16 + lk * 4;
      int col = bn + wc + ni * 16 + lr;
#pragma unroll
      for (int r = 0; r < 4; r++) {
        float v = acc[mi][ni][r];
        if (EPI == 0) {
          C[(size_t)(row + r) * ldc + col] = v;
        } else if (EPI == 1) {
          v += bias[col];
          C[(size_t)(row + r) * ldc + col] = (v > 20.f) ? v : log1pf(__expf(v));
        } else {
          atomicAdd(&C[(size_t)(row + r) * ldc + col], v);
        }
      }
    }
  }
}

// ---------------- conv (depthwise, causal, D_CONV=4) + silu ----------------
__global__ __launch_bounds__(256) void conv_silu_k(const float* __restrict__ xz,
                                                   const float* __restrict__ cw,
                                                   const float* __restrict__ cb,
                                                   float* __restrict__ xact,
                                                   ushort* __restrict__ xact_bf) {
  int idx = blockIdx.x * 256 + threadIdx.x;  // L*DINNER
  int t = idx >> 11, d = idx & 2047;
  float s = cb[d];
#pragma unroll
  for (int k = 0; k < 4; k++) {
    int tt = t + k - 3;
    if (tt >= 0) s += cw[d * 4 + k] * xz[(size_t)tt * 4096 + d];
  }
  float xa = s / (1.f + __expf(-s));
  xact[idx] = xa;
  xact_bf[idx] = f2b(xa);
}

// ---------------- selective scan (fused, + D*x + silu(z) gating) ----------------
__global__ __launch_bounds__(256) void scan_k(
    const float* __restrict__ dtp, const float* __restrict__ xact,
    const float* __restrict__ xdbl, const float* __restrict__ xz,
    const float* __restrict__ A_log, const float* __restrict__ Dp,
    ushort* __restrict__ ygate) {
  __shared__ float sBC[64][32];
  __shared__ float sdt[64][16];
  __shared__ float sx[64][16];
  __shared__ float sz[64][16];
  __shared__ float sy[64][16];
  const int tid = threadIdx.x;
  const int d0 = blockIdx.x * 16;
  const int dl = tid >> 4, n = tid & 15;
  const int d = d0 + dl;
  const float A_dn = -__expf(A_log[d * 16 + n]);
  const float Dd = Dp[d];
  const int r = tid >> 2, c4 = tid & 3;
  float h = 0.f;
  for (int t0 = 0; t0 < LSEQ; t0 += 64) {
    const float* bsrc = &xdbl[(size_t)(t0 + r) * 128 + 64 + c4 * 8];
    *(float4*)&sBC[r][c4 * 8] = *(const float4*)bsrc;
    *(float4*)&sBC[r][c4 * 8 + 4] = *(const float4*)(bsrc + 4);
    *(float4*)&sdt[r][c4 * 4] = *(const float4*)&dtp[(size_t)(t0 + r) * 2048 + d0 + c4 * 4];
    *(float4*)&sx[r][c4 * 4] = *(const float4*)&xact[(size_t)(t0 + r) * 2048 + d0 + c4 * 4];
    *(float4*)&sz[r][c4 * 4] =
        *(const float4*)&xz[(size_t)(t0 + r) * 4096 + 2048 + d0 + c4 * 4];
    __syncthreads();
    for (int i = 0; i < 64; i++) {
      float dtv = sdt[i][dl];
      float xv = sx[i][dl];
      h = __expf(dtv * A_dn) * h + (dtv * xv) * sBC[i][n];
      float pp = h * sBC[i][16 + n];
      pp += __shfl_xor(pp, 1, 16);
      pp += __shfl_xor(pp, 2, 16);
      pp += __shfl_xor(pp, 4, 16);
      pp += __shfl_xor(pp, 8, 16);
      if (n == 0) {
        float zv = sz[i][dl];
        sy[i][dl] = (pp + Dd * xv) * (zv / (1.f + __expf(-zv)));
      }
    }
    __syncthreads();
    {
      int cc = c4 * 4;
      float4 v = *(float4*)&sy[r][cc];
      ushort4 o;
      o.x = f2b(v.x); o.y = f2b(v.y); o.z = f2b(v.z); o.w = f2b(v.w);
      *(ushort4*)&ygate[(size_t)(t0 + r) * 2048 + d0 + cc] = o;
    }
    __syncthreads();
  }
}

// ---------------- softmax (fp32 in, bf16 out) ----------------
__global__ __launch_bounds__(256) void softmax_k(const float* __restrict__ logits,
                                                 ushort* __restrict__ att) {
  __shared__ float red[4];
  const int row = blockIdx.x, tid = threadIdx.x;
  const int wid = tid >> 6, lane = tid & 63;
  float l[8];
  float m = -1e30f;
#pragma unroll
  for (int j = 0; j < 8; j++) {
    l[j] = logits[(size_t)row * 2048 + j * 256 + tid];
    m = fmaxf(m, l[j]);
  }
#pragma unroll
  for (int o = 32; o >= 1; o >>= 1) m = fmaxf(m, __shfl_xor(m, o, 64));
  if (lane == 0) red[wid] = m;
  __syncthreads();
  m = fmaxf(fmaxf(red[0], red[1]), fmaxf(red[2], red[3]));
  __syncthreads();
  float s = 0.f;
#pragma unroll
  for (int j = 0; j < 8; j++) {
    l[j] = __expf(l[j] - m);
    s += l[j];
  }
#pragma unroll
  for (int o = 32; o >= 1; o >>= 1) s += __shfl_xor(s, o, 64);
  if (lane == 0) red[wid] = s;
  __syncthreads();
  s = red[0] + red[1] + red[2] + red[3];
  float inv = 1.f / s;
#pragma unroll
  for (int j = 0; j < 8; j++)
    att[(size_t)row * 2048 + j * 256 + tid] = f2b(l[j] * inv);
}

// ---------------- residual assemble + row L2 normalize ----------------
__global__ __launch_bounds__(256) void norm_k(const float* __restrict__ cam,
                                              const float* __restrict__ mamba,
                                              const float* __restrict__ img,
                                              const float* __restrict__ alpha,
                                              float* __restrict__ out) {
  __shared__ float red[4];
  const int row = blockIdx.x, tid = threadIdx.x;
  const int wid = tid >> 6, lane = tid & 63;
  const float a = alpha[0];
  float v[4];
  float ss = 0.f;
#pragma unroll
  for (int j = 0; j < 4; j++) {
    int c = j * 256 + tid;
    float m = mamba[(size_t)row * 1024 + c];
    float rr = (c < 512) ? (a * cam[(size_t)row * 512 + c] + m)
                         : (img[(size_t)row * 512 + (c - 512)] + m);
    v[j] = rr;
    ss += rr * rr;
  }
#pragma unroll
  for (int o = 32; o >= 1; o >>= 1) ss += __shfl_xor(ss, o, 64);
  if (lane == 0) red[wid] = ss;
  __syncthreads();
  ss = red[0] + red[1] + red[2] + red[3];
  float inv = 1.f / fmaxf(sqrtf(ss), 1e-12f);
#pragma unroll
  for (int j = 0; j < 4; j++) {
    int c = j * 256 + tid;
    float o = v[j] * inv;
    if (c < 512) out[(size_t)row * 512 + c] = o;
    else out[(size_t)(2048 * 512) + (size_t)row * 512 + (c - 512)] = o;
  }
}

// ---------------- host ----------------
extern "C" void kernel_launch(void* const* d_in, const int* in_sizes, int n_in,
                              void* d_out, int out_size, void* d_ws, size_t ws_size,
                              hipStream_t stream) {
  const float* image = (const float*)d_in[0];
  const float* text = (const float*)d_in[1];
  const float* w_in = (const float*)d_in[2];
  const float* conv_w = (const float*)d_in[3];
  const float* conv_b = (const float*)d_in[4];
  const float* w_xp = (const float*)d_in[5];
  const float* w_dt = (const float*)d_in[6];
  const float* b_dt = (const float*)d_in[7];
  const float* A_log = (const float*)d_in[8];
  const float* Dp = (const float*)d_in[9];
  const float* w_out = (const float*)d_in[10];
  const float* alpha = (const float*)d_in[11];
  float* out = (float*)d_out;

  char* p = (char*)d_ws;
  auto alloc = [&](size_t bytes) -> char* {
    char* r = p;
    p += (bytes + 255) & ~(size_t)255;
    return r;
  };
  ushort* tokens_bf = (ushort*)alloc((size_t)LSEQ * DMODEL * 2);
  ushort* w_in_bf = (ushort*)alloc((size_t)4096 * 1024 * 2);
  ushort* w_xp_bf = (ushort*)alloc((size_t)128 * 2048 * 2);
  ushort* w_dt_bf = (ushort*)alloc((size_t)2048 * 64 * 2);
  ushort* w_out_bf = (ushort*)alloc((size_t)1024 * 2048 * 2);
  ushort* Aext = (ushort*)alloc((size_t)LSEQ * 1536 * 2);
  ushort* Bext = (ushort*)alloc((size_t)LSEQ * 1536 * 2);
  ushort* textT = (ushort*)alloc((size_t)512 * 2048 * 2);
  float* xz = (float*)alloc((size_t)LSEQ * 4096 * 4);
  float* xact = (float*)alloc((size_t)LSEQ * 2048 * 4);
  ushort* xact_bf = (ushort*)alloc((size_t)LSEQ * 2048 * 2);
  float* xdbl = (float*)alloc((size_t)LSEQ * 128 * 4);
  ushort* dtr_bf = (ushort*)alloc((size_t)LSEQ * 64 * 2);
  float* dtp = (float*)alloc((size_t)LSEQ * 2048 * 4);
  ushort* ygate = (ushort*)alloc((size_t)LSEQ * 2048 * 2);
  float* mamba = (float*)alloc((size_t)LSEQ * 1024 * 4);
  float* logits = (float*)alloc((size_t)LSEQ * 2048 * 4);
  ushort* att_bf = (ushort*)alloc((size_t)LSEQ * 2048 * 2);
  float* cam = (float*)alloc((size_t)LSEQ * 512 * 4);

  // prep
  convert_k<<<(4096 * 1024 + 255) / 256, 256, 0, stream>>>(w_in, w_in_bf, 4096 * 1024);
  convert_k<<<(1024 * 2048 + 255) / 256, 256, 0, stream>>>(w_out, w_out_bf, 1024 * 2048);
  convert_k<<<(2048 * 64 + 255) / 256, 256, 0, stream>>>(w_dt, w_dt_bf, 2048 * 64);
  tokens_k<<<(LSEQ * DMODEL) / 256, 256, 0, stream>>>(image, text, tokens_bf);
  xproj_pad_k<<<(128 * 2048) / 256, 256, 0, stream>>>(w_xp, w_xp_bf);
  attn_ext_k<<<(LSEQ * 512) / 256, 256, 0, stream>>>(image, text, Aext, Bext);
  textT_k<<<dim3(16, 64), 256, 0, stream>>>(text, textT);

  hipMemsetAsync(xdbl, 0, (size_t)LSEQ * 128 * 4, stream);
  hipMemsetAsync(mamba, 0, (size_t)LSEQ * 1024 * 4, stream);
  hipMemsetAsync(cam, 0, (size_t)LSEQ * 512 * 4, stream);

  // mamba branch
  gemm_bf16_k<0><<<dim3(32, 16, 1), 256, 0, stream>>>(
      tokens_bf, w_in_bf, xz, nullptr, 2048, 4096, 1024, 1024, 1024, 4096, 1024);
  conv_silu_k<<<(LSEQ * DINNER) / 256, 256, 0, stream>>>(xz, conv_w, conv_b, xact, xact_bf);
  gemm_bf16_k<2><<<dim3(1, 16, 4), 256, 0, stream>>>(
      xact_bf, w_xp_bf, xdbl, nullptr, 2048, 128, 2048, 2048, 2048, 128, 512);
  dtr_k<<<(LSEQ * 64) / 256, 256, 0, stream>>>(xdbl, dtr_bf);
  gemm_bf16_k<1><<<dim3(16, 16, 1), 256, 0, stream>>>(
      dtr_bf, w_dt_bf, dtp, b_dt, 2048, 2048, 64, 64, 64, 2048, 64);
  scan_k<<<128, 256, 0, stream>>>(dtp, xact, xdbl, xz, A_log, Dp, ygate);
  gemm_bf16_k<2><<<dim3(8, 16, 2), 256, 0, stream>>>(
      ygate, w_out_bf, mamba, nullptr, 2048, 1024, 2048, 2048, 2048, 1024, 1024);

  // attention branch (split-bf16 logits for fp32-grade precision)
  gemm_bf16_k<0><<<dim3(16, 16, 1), 256, 0, stream>>>(
      Aext, Bext, logits, nullptr, 2048, 2048, 1536, 1536, 1536, 2048, 1536);
  softmax_k<<<2048, 256, 0, stream>>>(logits, att_bf);
  gemm_bf16_k<2><<<dim3(4, 16, 4), 256, 0, stream>>>(
      att_bf, textT, cam, nullptr, 2048, 512, 2048, 2048, 2048, 512, 512);

  // assemble + normalize
  norm_k<<<2048, 256, 0, stream>>>(cam, mamba, image, alpha, out);
}

// Round 2
// 307.667 us; speedup vs baseline: 2.4496x; 2.4496x over previous
//
#include <hip/hip_runtime.h>
#include <hip/hip_bf16.h>

#define LSEQ 2048
#define DMODEL 1024
#define OUTD 512
#define DSTATE 16
#define DINNER 2048
#define DTRANK 64
#define NCHUNK 64
#define CHUNK 32

typedef __attribute__((ext_vector_type(8))) short bf16x8;
typedef __attribute__((ext_vector_type(4))) float f32x4;

__device__ __forceinline__ ushort f2b(float f) {
  __hip_bfloat16 h = __float2bfloat16(f);
  return *reinterpret_cast<ushort*>(&h);
}
__device__ __forceinline__ float b2f(ushort u) {
  __hip_bfloat16 h = *reinterpret_cast<__hip_bfloat16*>(&u);
  return __bfloat162float(h);
}

// ---------------- prep kernels ----------------
__global__ __launch_bounds__(256) void convert_k(const float* __restrict__ in,
                                                 ushort* __restrict__ out, int n) {
  int i = blockIdx.x * 256 + threadIdx.x;
  if (i < n) out[i] = f2b(in[i]);
}

__global__ __launch_bounds__(256) void tokens_k(const float* __restrict__ img,
                                                const float* __restrict__ txt,
                                                ushort* __restrict__ out) {
  int i = blockIdx.x * 256 + threadIdx.x;  // L*DMODEL
  int r = i >> 10, c = i & 1023;
  float v = (c < 512) ? img[r * 512 + c] : txt[r * 512 + c - 512];
  out[i] = f2b(v);
}

__global__ __launch_bounds__(256) void xproj_pad_k(const float* __restrict__ w,
                                                   ushort* __restrict__ out) {
  int i = blockIdx.x * 256 + threadIdx.x;  // 128*2048
  int r = i >> 11, c = i & 2047;
  out[i] = (r < 96) ? f2b(w[r * 2048 + c]) : (ushort)0;
}

// A' = [hi(img) | lo(img) | hi(img)], B' = [hi(txt) | hi(txt) | lo(txt)]
__global__ __launch_bounds__(256) void attn_ext_k(const float* __restrict__ img,
                                                  const float* __restrict__ txt,
                                                  ushort* __restrict__ Ae,
                                                  ushort* __restrict__ Be) {
  int i = blockIdx.x * 256 + threadIdx.x;  // L*512
  int r = i >> 9, c = i & 511;
  float a = img[i], b = txt[i];
  ushort ah = f2b(a); ushort al = f2b(a - b2f(ah));
  ushort bh = f2b(b); ushort bl = f2b(b - b2f(bh));
  size_t base = (size_t)r * 1536;
  Ae[base + c] = ah; Ae[base + 512 + c] = al; Ae[base + 1024 + c] = ah;
  Be[base + c] = bh; Be[base + 512 + c] = bh; Be[base + 1024 + c] = bl;
}

__global__ __launch_bounds__(256) void textT_k(const float* __restrict__ txt,
                                               ushort* __restrict__ out) {
  __shared__ float tile[32][33];
  int bx = blockIdx.x, by = blockIdx.y;          // bx over 512/32, by over 2048/32
  int tx = threadIdx.x & 31, ty = threadIdx.x >> 5;  // 32 x 8
  for (int j = 0; j < 32; j += 8)
    tile[ty + j][tx] = txt[(size_t)(by * 32 + ty + j) * 512 + bx * 32 + tx];
  __syncthreads();
  for (int j = 0; j < 32; j += 8)
    out[(size_t)(bx * 32 + ty + j) * 2048 + by * 32 + tx] = f2b(tile[tx][ty + j]);
}

__global__ __launch_bounds__(256) void dtr_k(const float* __restrict__ xdbl,
                                             ushort* __restrict__ out) {
  int i = blockIdx.x * 256 + threadIdx.x;  // L*64
  int r = i >> 6, c = i & 63;
  out[i] = f2b(xdbl[r * 128 + c]);
}

// ---------------- GEMM (bf16 MFMA, 128x128 tile, BK=32) ----------------
template <int EPI>
__global__ __launch_bounds__(256) void gemm_bf16_k(
    const ushort* __restrict__ A, const ushort* __restrict__ B,
    float* __restrict__ C, const float* __restrict__ bias,
    int M, int N, int K, int lda, int ldb, int ldc, int kPerSplit) {
  __shared__ ushort As[128 * 32];
  __shared__ ushort Bs[128 * 32];
  const int bm = blockIdx.y * 128, bn = blockIdx.x * 128;
  const int tid = threadIdx.x;
  const int w = tid >> 6, lane = tid & 63;
  const int wr = (w >> 1) * 64, wc = (w & 1) * 64;
  const int lr = lane & 15, lk = lane >> 4;
  const int srow = tid >> 2, scol = (tid & 3) * 8;
  const int k0 = blockIdx.z * kPerSplit;
  const int k1 = k0 + kPerSplit;
  f32x4 acc[4][4] = {};
  for (int kt = k0; kt < k1; kt += 32) {
    *(int4*)&As[srow * 32 + scol] =
        *(const int4*)&A[(size_t)(bm + srow) * lda + kt + scol];
    *(int4*)&As[(srow + 64) * 32 + scol] =
        *(const int4*)&A[(size_t)(bm + srow + 64) * lda + kt + scol];
    *(int4*)&Bs[srow * 32 + scol] =
        *(const int4*)&B[(size_t)(bn + srow) * ldb + kt + scol];
    *(int4*)&Bs[(srow + 64) * 32 + scol] =
        *(const int4*)&B[(size_t)(bn + srow + 64) * ldb + kt + scol];
    __syncthreads();
    bf16x8 af[4], bfr[4];
#pragma unroll
    for (int i = 0; i < 4; i++) af[i] = *(bf16x8*)&As[(wr + i * 16 + lr) * 32 + lk * 8];
#pragma unroll
    for (int i = 0; i < 4; i++) bfr[i] = *(bf16x8*)&Bs[(wc + i * 16 + lr) * 32 + lk * 8];
#pragma unroll
    for (int mi = 0; mi < 4; mi++)
#pragma unroll
      for (int ni = 0; ni < 4; ni++)
        acc[mi][ni] = __builtin_amdgcn_mfma_f32_16x16x32_bf16(af[mi], bfr[ni],
                                                              acc[mi][ni], 0, 0, 0);
    __syncthreads();
  }
#pragma unroll
  for (int mi = 0; mi < 4; mi++) {
#pragma unroll
    for (int ni = 0; ni < 4; ni++) {
      int row = bm + wr + mi * 16 + lk * 4;
      int col = bn + wc + ni * 16 + lr;
#pragma unroll
      for (int r = 0; r < 4; r++) {
        float v = acc[mi][ni][r];
        if (EPI == 0) {
          C[(size_t)(row + r) * ldc + col] = v;
        } else if (EPI == 1) {
          v += bias[col];
          C[(size_t)(row + r) * ldc + col] = (v > 20.f) ? v : log1pf(__expf(v));
        } else {
          atomicAdd(&C[(size_t)(row + r) * ldc + col], v);
        }
      }
    }
  }
}

// ---------------- conv (depthwise, causal, D_CONV=4) + silu ----------------
__global__ __launch_bounds__(256) void conv_silu_k(const float* __restrict__ xz,
                                                   const float* __restrict__ cw,
                                                   const float* __restrict__ cb,
                                                   float* __restrict__ xact,
                                                   ushort* __restrict__ xact_bf) {
  int idx = blockIdx.x * 256 + threadIdx.x;  // L*DINNER
  int t = idx >> 11, d = idx & 2047;
  float s = cb[d];
#pragma unroll
  for (int k = 0; k < 4; k++) {
    int tt = t + k - 3;
    if (tt >= 0) s += cw[d * 4 + k] * xz[(size_t)tt * 4096 + d];
  }
  float xa = s / (1.f + __expf(-s));
  xact[idx] = xa;
  xact_bf[idx] = f2b(xa);
}

// ---------------- selective scan: chunk-parallel, 3 passes ----------------
// pass 1: per-chunk local scan from h=0; store final h and product P.
__global__ __launch_bounds__(256) void scan1_k(
    const float* __restrict__ dtp, const float* __restrict__ xact,
    const float* __restrict__ xdbl, const float* __restrict__ A_log,
    float* __restrict__ hfin, float* __restrict__ Pfin) {
  __shared__ float sB[CHUNK][16];
  const int tid = threadIdx.x;
  const int d = blockIdx.x * 256 + tid;
  const int c = blockIdx.y;
  if (tid < CHUNK * 4) {
    int r = tid >> 2, q = tid & 3;
    *(float4*)&sB[r][q * 4] =
        *(const float4*)&xdbl[(size_t)(c * CHUNK + r) * 128 + 64 + q * 4];
  }
  float Ad[16];
#pragma unroll
  for (int n = 0; n < 16; n += 4) *(float4*)&Ad[n] = *(const float4*)&A_log[d * 16 + n];
#pragma unroll
  for (int n = 0; n < 16; n++) Ad[n] = -__expf(Ad[n]);
  __syncthreads();
  float h[16] = {};
  float P[16];
#pragma unroll
  for (int n = 0; n < 16; n++) P[n] = 1.f;
  for (int t = 0; t < CHUNK; t++) {
    int tt = c * CHUNK + t;
    float dtv = dtp[(size_t)tt * 2048 + d];
    float xv = xact[(size_t)tt * 2048 + d];
    float u = dtv * xv;
#pragma unroll
    for (int n = 0; n < 16; n++) {
      float e = __expf(dtv * Ad[n]);
      h[n] = e * h[n] + u * sB[t][n];
      P[n] *= e;
    }
  }
  size_t base = ((size_t)c * 2048 + d) * 16;
#pragma unroll
  for (int n = 0; n < 16; n += 4) {
    *(float4*)&hfin[base + n] = *(float4*)&h[n];
    *(float4*)&Pfin[base + n] = *(float4*)&P[n];
  }
}

// pass 2: sequential combine over chunk summaries -> per-chunk initial state H0.
__global__ __launch_bounds__(256) void scan2_k(const float* __restrict__ hfin,
                                               const float* __restrict__ Pfin,
                                               float* __restrict__ H0) {
  int idx = blockIdx.x * 256 + threadIdx.x;  // 2048*16
  float H = 0.f;
  for (int c = 0; c < NCHUNK; c++) {
    size_t o = (size_t)c * 32768 + idx;
    H0[o] = H;
    H = Pfin[o] * H + hfin[o];
  }
}

// pass 3: replay chunk with seeded state; fused y = C.h + D*x, gated by silu(z).
__global__ __launch_bounds__(256) void scan3_k(
    const float* __restrict__ dtp, const float* __restrict__ xact,
    const float* __restrict__ xdbl, const float* __restrict__ xz,
    const float* __restrict__ A_log, const float* __restrict__ Dp,
    const float* __restrict__ H0, ushort* __restrict__ ygate) {
  __shared__ float sBC[CHUNK][32];
  const int tid = threadIdx.x;
  const int d = blockIdx.x * 256 + tid;
  const int c = blockIdx.y;
  {
    int r = tid >> 3, q = tid & 7;
    *(float4*)&sBC[r][q * 4] =
        *(const float4*)&xdbl[(size_t)(c * CHUNK + r) * 128 + 64 + q * 4];
  }
  float Ad[16];
#pragma unroll
  for (int n = 0; n < 16; n += 4) *(float4*)&Ad[n] = *(const float4*)&A_log[d * 16 + n];
#pragma unroll
  for (int n = 0; n < 16; n++) Ad[n] = -__expf(Ad[n]);
  float h[16];
  size_t hbase = ((size_t)c * 2048 + d) * 16;
#pragma unroll
  for (int n = 0; n < 16; n += 4) *(float4*)&h[n] = *(const float4*)&H0[hbase + n];
  const float Dd = Dp[d];
  __syncthreads();
  for (int t = 0; t < CHUNK; t++) {
    int tt = c * CHUNK + t;
    float dtv = dtp[(size_t)tt * 2048 + d];
    float xv = xact[(size_t)tt * 2048 + d];
    float zv = xz[(size_t)tt * 4096 + 2048 + d];
    float u = dtv * xv;
    float y = Dd * xv;
#pragma unroll
    for (int n = 0; n < 16; n++) {
      float e = __expf(dtv * Ad[n]);
      h[n] = e * h[n] + u * sBC[t][n];
      y += h[n] * sBC[t][16 + n];
    }
    float g = zv / (1.f + __expf(-zv));
    ygate[(size_t)tt * 2048 + d] = f2b(y * g);
  }
}

// ---------------- softmax (fp32 in, bf16 out) ----------------
__global__ __launch_bounds__(256) void softmax_k(const float* __restrict__ logits,
                                                 ushort* __restrict__ att) {
  __shared__ float red[4];
  const int row = blockIdx.x, tid = threadIdx.x;
  const int wid = tid >> 6, lane = tid & 63;
  float l[8];
  float m = -1e30f;
#pragma unroll
  for (int j = 0; j < 8; j++) {
    l[j] = logits[(size_t)row * 2048 + j * 256 + tid];
    m = fmaxf(m, l[j]);
  }
#pragma unroll
  for (int o = 32; o >= 1; o >>= 1) m = fmaxf(m, __shfl_xor(m, o, 64));
  if (lane == 0) red[wid] = m;
  __syncthreads();
  m = fmaxf(fmaxf(red[0], red[1]), fmaxf(red[2], red[3]));
  __syncthreads();
  float s = 0.f;
#pragma unroll
  for (int j = 0; j < 8; j++) {
    l[j] = __expf(l[j] - m);
    s += l[j];
  }
#pragma unroll
  for (int o = 32; o >= 1; o >>= 1) s += __shfl_xor(s, o, 64);
  if (lane == 0) red[wid] = s;
  __syncthreads();
  s = red[0] + red[1] + red[2] + red[3];
  float inv = 1.f / s;
#pragma unroll
  for (int j = 0; j < 8; j++)
    att[(size_t)row * 2048 + j * 256 + tid] = f2b(l[j] * inv);
}

// ---------------- residual assemble + row L2 normalize ----------------
__global__ __launch_bounds__(256) void norm_k(const float* __restrict__ cam,
                                              const float* __restrict__ mamba,
                                              const float* __restrict__ img,
                                              const float* __restrict__ alpha,
                                              float* __restrict__ out) {
  __shared__ float red[4];
  const int row = blockIdx.x, tid = threadIdx.x;
  const int wid = tid >> 6, lane = tid & 63;
  const float a = alpha[0];
  float v[4];
  float ss = 0.f;
#pragma unroll
  for (int j = 0; j < 4; j++) {
    int c = j * 256 + tid;
    float m = mamba[(size_t)row * 1024 + c];
    float rr = (c < 512) ? (a * cam[(size_t)row * 512 + c] + m)
                         : (img[(size_t)row * 512 + (c - 512)] + m);
    v[j] = rr;
    ss += rr * rr;
  }
#pragma unroll
  for (int o = 32; o >= 1; o >>= 1) ss += __shfl_xor(ss, o, 64);
  if (lane == 0) red[wid] = ss;
  __syncthreads();
  ss = red[0] + red[1] + red[2] + red[3];
  float inv = 1.f / fmaxf(sqrtf(ss), 1e-12f);
#pragma unroll
  for (int j = 0; j < 4; j++) {
    int c = j * 256 + tid;
    float o = v[j] * inv;
    if (c < 512) out[(size_t)row * 512 + c] = o;
    else out[(size_t)(2048 * 512) + (size_t)row * 512 + (c - 512)] = o;
  }
}

// ---------------- host ----------------
extern "C" void kernel_launch(void* const* d_in, const int* in_sizes, int n_in,
                              void* d_out, int out_size, void* d_ws, size_t ws_size,
                              hipStream_t stream) {
  const float* image = (const float*)d_in[0];
  const float* text = (const float*)d_in[1];
  const float* w_in = (const float*)d_in[2];
  const float* conv_w = (const float*)d_in[3];
  const float* conv_b = (const float*)d_in[4];
  const float* w_xp = (const float*)d_in[5];
  const float* w_dt = (const float*)d_in[6];
  const float* b_dt = (const float*)d_in[7];
  const float* A_log = (const float*)d_in[8];
  const float* Dp = (const float*)d_in[9];
  const float* w_out = (const float*)d_in[10];
  const float* alpha = (const float*)d_in[11];
  float* out = (float*)d_out;

  char* p = (char*)d_ws;
  auto alloc = [&](size_t bytes) -> char* {
    char* r = p;
    p += (bytes + 255) & ~(size_t)255;
    return r;
  };
  ushort* tokens_bf = (ushort*)alloc((size_t)LSEQ * DMODEL * 2);
  ushort* w_in_bf = (ushort*)alloc((size_t)4096 * 1024 * 2);
  ushort* w_xp_bf = (ushort*)alloc((size_t)128 * 2048 * 2);
  ushort* w_dt_bf = (ushort*)alloc((size_t)2048 * 64 * 2);
  ushort* w_out_bf = (ushort*)alloc((size_t)1024 * 2048 * 2);
  ushort* Aext = (ushort*)alloc((size_t)LSEQ * 1536 * 2);
  ushort* Bext = (ushort*)alloc((size_t)LSEQ * 1536 * 2);
  ushort* textT = (ushort*)alloc((size_t)512 * 2048 * 2);
  float* xz = (float*)alloc((size_t)LSEQ * 4096 * 4);
  float* xact = (float*)alloc((size_t)LSEQ * 2048 * 4);
  ushort* xact_bf = (ushort*)alloc((size_t)LSEQ * 2048 * 2);
  float* xdbl = (float*)alloc((size_t)LSEQ * 128 * 4);
  ushort* dtr_bf = (ushort*)alloc((size_t)LSEQ * 64 * 2);
  float* dtp = (float*)alloc((size_t)LSEQ * 2048 * 4);
  ushort* ygate = (ushort*)alloc((size_t)LSEQ * 2048 * 2);
  float* mamba = (float*)alloc((size_t)LSEQ * 1024 * 4);
  float* logits = (float*)alloc((size_t)LSEQ * 2048 * 4);
  ushort* att_bf = (ushort*)alloc((size_t)LSEQ * 2048 * 2);
  float* cam = (float*)alloc((size_t)LSEQ * 512 * 4);
  float* hfin = (float*)alloc((size_t)NCHUNK * 2048 * 16 * 4);
  float* Pfin = (float*)alloc((size_t)NCHUNK * 2048 * 16 * 4);
  float* H0 = (float*)alloc((size_t)NCHUNK * 2048 * 16 * 4);

  // prep
  convert_k<<<(4096 * 1024 + 255) / 256, 256, 0, stream>>>(w_in, w_in_bf, 4096 * 1024);
  convert_k<<<(1024 * 2048 + 255) / 256, 256, 0, stream>>>(w_out, w_out_bf, 1024 * 2048);
  convert_k<<<(2048 * 64 + 255) / 256, 256, 0, stream>>>(w_dt, w_dt_bf, 2048 * 64);
  tokens_k<<<(LSEQ * DMODEL) / 256, 256, 0, stream>>>(image, text, tokens_bf);
  xproj_pad_k<<<(128 * 2048) / 256, 256, 0, stream>>>(w_xp, w_xp_bf);
  attn_ext_k<<<(LSEQ * 512) / 256, 256, 0, stream>>>(image, text, Aext, Bext);
  textT_k<<<dim3(16, 64), 256, 0, stream>>>(text, textT);

  hipMemsetAsync(xdbl, 0, (size_t)LSEQ * 128 * 4, stream);
  hipMemsetAsync(mamba, 0, (size_t)LSEQ * 1024 * 4, stream);
  hipMemsetAsync(cam, 0, (size_t)LSEQ * 512 * 4, stream);

  // mamba branch
  gemm_bf16_k<0><<<dim3(32, 16, 1), 256, 0, stream>>>(
      tokens_bf, w_in_bf, xz, nullptr, 2048, 4096, 1024, 1024, 1024, 4096, 1024);
  conv_silu_k<<<(LSEQ * DINNER) / 256, 256, 0, stream>>>(xz, conv_w, conv_b, xact, xact_bf);
  gemm_bf16_k<2><<<dim3(1, 16, 4), 256, 0, stream>>>(
      xact_bf, w_xp_bf, xdbl, nullptr, 2048, 128, 2048, 2048, 2048, 128, 512);
  dtr_k<<<(LSEQ * 64) / 256, 256, 0, stream>>>(xdbl, dtr_bf);
  gemm_bf16_k<1><<<dim3(16, 16, 1), 256, 0, stream>>>(
      dtr_bf, w_dt_bf, dtp, b_dt, 2048, 2048, 64, 64, 64, 2048, 64);
  scan1_k<<<dim3(8, NCHUNK), 256, 0, stream>>>(dtp, xact, xdbl, A_log, hfin, Pfin);
  scan2_k<<<128, 256, 0, stream>>>(hfin, Pfin, H0);
  scan3_k<<<dim3(8, NCHUNK), 256, 0, stream>>>(dtp, xact, xdbl, xz, A_log, Dp, H0, ygate);
  gemm_bf16_k<2><<<dim3(8, 16, 2), 256, 0, stream>>>(
      ygate, w_out_bf, mamba, nullptr, 2048, 1024, 2048, 2048, 2048, 1024, 1024);

  // attention branch (split-bf16 logits for fp32-grade precision)
  gemm_bf16_k<0><<<dim3(16, 16, 1), 256, 0, stream>>>(
      Aext, Bext, logits, nullptr, 2048, 2048, 1536, 1536, 1536, 2048, 1536);
  softmax_k<<<2048, 256, 0, stream>>>(logits, att_bf);
  gemm_bf16_k<2><<<dim3(4, 16, 4), 256, 0, stream>>>(
      att_bf, textT, cam, nullptr, 2048, 512, 2048, 2048, 2048, 512, 512);

  // assemble + normalize
  norm_k<<<2048, 256, 0, stream>>>(cam, mamba, image, alpha, out);
}